// Round 9
// baseline (724.300 us; speedup 1.0000x reference)
//
#include <hip/hip_runtime.h>
#include <hip/hip_fp16.h>

// GCN 2-layer forward: out = softmax( A_norm @ relu(A_norm @ (x@W1) + b1) @ W2 + b2 )
// A_norm = D^-1/2 (A + I) D^-1/2, edges are col->row (row = target).
//
// R8 -> R9: per-kernel work (~95us) no longer dominates — ~45us of the 182 is
// inter-dispatch gap (7 launches). Fuse everything into ONE persistent kernel
// with device-scope grid barriers:
//   P1 hist -> P2 bin -> P3 per-bucket sort+gemm(MFMA, dinv via LDS)
//   -> P4 agg1 -> P5 agg2
// Co-residency (sanctioned pattern): __launch_bounds__(256,5) => >=5 blocks/CU
// by VGPR; LDS 18.5KB (bin tile 2048, gbase in-place) => 8/CU by LDS; grid
// 1120 < 1280 capacity. Barriers: per-phase counters in d_ws (memset-zeroed,
// one contiguous exact block — R4 lesson), __threadfence + device atomics.

typedef _Float16 f16x8 __attribute__((ext_vector_type(8)));
typedef float f32x4 __attribute__((ext_vector_type(4)));

#define GRID_BLOCKS 1120

union SmemU {
    int cnt1[392];                                 // P1
    struct {                                       // P2 (18560 B = max)
        unsigned items[2048];
        unsigned short bktid[2048];
        int cnt[392];      // after scan+transform: gbase
        int start0[392];
        int cursor[392];
        int gb[392];
    } p2;
    struct {                                       // P3 (5 KB)
        int ps[256];
        int cnt[256];
        int tmp[256];
        int cur[256];
        float sdinv[256];
    } p3;
};

__device__ __forceinline__ void gsync(int* bar, int slot) {
    __syncthreads();
    if (threadIdx.x == 0) {
        __threadfence();                            // flush block's writes (agent scope)
        atomicAdd(&bar[slot], 1);                   // device-scope by default
        while (atomicAdd(&bar[slot], 0) < (int)gridDim.x)
            __builtin_amdgcn_s_sleep(2);
        __threadfence();
    }
    __syncthreads();
}

__global__ __launch_bounds__(256, 5) void k_mega(
    const float* __restrict__ x, const int* __restrict__ row, const int* __restrict__ col,
    const float* __restrict__ W1, const float* __restrict__ b1,
    const float* __restrict__ W2, const float* __restrict__ b2,
    int* __restrict__ ctrl,        // [0..15] barriers | [16..407] bcnt | [408..799] relcur
    int* __restrict__ offsets, float* __restrict__ dinv,
    unsigned* __restrict__ pairbuf, int* __restrict__ scol,
    __half* __restrict__ hp, float2* __restrict__ h2p,
    float2* __restrict__ out, int N, int E, int nb)
{
    __shared__ SmemU sm;
    int* bar = ctrl;
    int* bcnt = ctrl + 16;
    int* relcur = ctrl + 408;
    const int tid = threadIdx.x;
    const int G = (int)gridDim.x;

    // ================= P1: per-bucket histogram (+ zero hp row N) ===========
    {
        for (int t = tid; t < nb; t += 256) sm.cnt1[t] = 0;
        __syncthreads();
        int chunk = (E + G - 1) / G;
        int lo = blockIdx.x * chunk;
        int hi = lo + chunk; if (hi > E) hi = E;
        for (int i = lo + tid; i < hi; i += 256) atomicAdd(&sm.cnt1[row[i] >> 8], 1);
        __syncthreads();
        for (int t = tid; t < nb; t += 256) {
            int v = sm.cnt1[t];
            if (v) atomicAdd(&bcnt[t], v);
        }
        if (blockIdx.x == 0 && tid < 32) ((int*)(hp + (size_t)N * 64))[tid] = 0;
    }
    gsync(bar, 0);

    // ================= P2: bin edges into buckets (tiles of 2048) ===========
    {
        int nT = (E + 2047) / 2048;
        for (int t = blockIdx.x; t < nT; t += G) {
            int base = t * 2048;
            int m = E - base; if (m > 2048) m = 2048;
            for (int i = tid; i < nb; i += 256) sm.p2.cnt[i] = 0;
            __syncthreads();
            for (int i = tid; i < m; i += 256) atomicAdd(&sm.p2.cnt[row[base + i] >> 8], 1);
            __syncthreads();
            if (tid < 64) {            // wave0: scan tile counts -> start0, cursor
                int lane = tid, running = 0;
                for (int ch = 0; ch < 7; ++ch) {
                    int idx = ch * 64 + lane;
                    int v = (idx < nb) ? sm.p2.cnt[idx] : 0;
                    int s = v;
#pragma unroll
                    for (int off = 1; off < 64; off <<= 1) {
                        int tt = __shfl_up(s, off, 64);
                        if (lane >= off) s += tt;
                    }
                    if (idx < nb) { sm.p2.start0[idx] = running + s - v; sm.p2.cursor[idx] = running + s - v; }
                    running += __shfl(s, 63, 64);
                }
            } else if (tid < 128) {    // wave1: scan global bcnt -> gb
                int lane = tid - 64, running = 0;
                for (int ch = 0; ch < 7; ++ch) {
                    int idx = ch * 64 + lane;
                    int v = (idx < nb) ? bcnt[idx] : 0;
                    int s = v;
#pragma unroll
                    for (int off = 1; off < 64; off <<= 1) {
                        int tt = __shfl_up(s, off, 64);
                        if (lane >= off) s += tt;
                    }
                    if (idx < nb) sm.p2.gb[idx] = running + s - v;
                    running += __shfl(s, 63, 64);
                }
            }
            __syncthreads();
            // gbase in place (cnt <- gb + relcur-claim), then stage items
            for (int i = tid; i < nb; i += 256) {
                int cv = sm.p2.cnt[i];
                if (cv > 0) sm.p2.cnt[i] = sm.p2.gb[i] + atomicAdd(&relcur[i], cv);
            }
            for (int i = tid; i < m; i += 256) {
                int r = row[base + i];
                int c = col[base + i];
                int b = r >> 8;
                int pos = atomicAdd(&sm.p2.cursor[b], 1);
                sm.p2.items[pos] = ((unsigned)(r & 255) << 24) | (unsigned)c;
                sm.p2.bktid[pos] = (unsigned short)b;
            }
            __syncthreads();
            for (int i = tid; i < m; i += 256) {
                int b = sm.p2.bktid[i];
                pairbuf[sm.p2.cnt[b] + (i - sm.p2.start0[b])] = sm.p2.items[i];
            }
            __syncthreads();
        }
    }
    gsync(bar, 1);

    // ================= P3: per-bucket counting sort + MFMA gemm =============
    {
        int lane = tid & 63, q = lane >> 4, mm = lane & 15;
        // B-frags (W1 fp16) once per wave: B[k][n], n = nt*16+mm, k = kk*32+q*8+j
        f16x8 bf[4][2];
#pragma unroll
        for (int nt = 0; nt < 4; ++nt)
#pragma unroll
            for (int kk = 0; kk < 2; ++kk)
#pragma unroll
                for (int j = 0; j < 8; ++j)
                    bf[nt][kk][j] = (_Float16)W1[(kk * 32 + q * 8 + j) * 64 + nt * 16 + mm];
        for (int b = blockIdx.x; b < nb; b += G) {
            int v = (tid < b) ? bcnt[tid] : 0;
            if (tid + 256 < b) v += bcnt[tid + 256];
            sm.p3.ps[tid] = v;
            __syncthreads();
            for (int s = 128; s >= 1; s >>= 1) {
                if (tid < s) sm.p3.ps[tid] += sm.p3.ps[tid + s];
                __syncthreads();
            }
            int lo = sm.p3.ps[0];
            int hi = lo + bcnt[b];
            sm.p3.cnt[tid] = 0;
            __syncthreads();
            for (int i = lo + tid; i < hi; i += 256) atomicAdd(&sm.p3.cnt[pairbuf[i] >> 24], 1);
            __syncthreads();
            int cv = sm.p3.cnt[tid];
            sm.p3.tmp[tid] = cv;
            __syncthreads();
            for (int d = 1; d < 256; d <<= 1) {
                int tt = (tid >= d) ? sm.p3.tmp[tid - d] : 0;
                __syncthreads();
                if (tid >= d) sm.p3.tmp[tid] += tt;
                __syncthreads();
            }
            int excl = sm.p3.tmp[tid] - cv;
            int n = (b << 8) + tid;
            float dv = rsqrtf((float)(cv + 1));     // +1 self-loop
            if (n < N) { offsets[n] = lo + excl; dinv[n] = dv; }
            sm.p3.sdinv[tid] = dv;
            sm.p3.cur[tid] = lo + excl;
            if (b == 0 && tid == 0) { offsets[N] = E; scol[E] = N; }  // sentinel
            __syncthreads();
            for (int i = lo + tid; i < hi; i += 256) {
                unsigned it = pairbuf[i];
                int pos = atomicAdd(&sm.p3.cur[it >> 24], 1);
                scol[pos] = (int)(it & 0xFFFFFFu);
            }
            __syncthreads();
            // gemm this bucket's nodes: hp = fp16(dinv * x@W1)
            int n0 = b << 8;
            int nn = N - n0; if (nn > 256) nn = 256;   // multiple of 16
            int wv = tid >> 6;
            for (int t = wv; t < (nn >> 4); t += 4) {
                const float* xrow = x + (size_t)(n0 + t * 16 + mm) * 64;
                float4 u0 = *(const float4*)(xrow + q * 8);
                float4 u1 = *(const float4*)(xrow + q * 8 + 4);
                float4 u2 = *(const float4*)(xrow + 32 + q * 8);
                float4 u3 = *(const float4*)(xrow + 32 + q * 8 + 4);
                f16x8 a0, a1;
                a0[0] = (_Float16)u0.x; a0[1] = (_Float16)u0.y; a0[2] = (_Float16)u0.z; a0[3] = (_Float16)u0.w;
                a0[4] = (_Float16)u1.x; a0[5] = (_Float16)u1.y; a0[6] = (_Float16)u1.z; a0[7] = (_Float16)u1.w;
                a1[0] = (_Float16)u2.x; a1[1] = (_Float16)u2.y; a1[2] = (_Float16)u2.z; a1[3] = (_Float16)u2.w;
                a1[4] = (_Float16)u3.x; a1[5] = (_Float16)u3.y; a1[6] = (_Float16)u3.z; a1[7] = (_Float16)u3.w;
                f32x4 ac0 = {0.f, 0.f, 0.f, 0.f}, ac1 = ac0, ac2 = ac0, ac3 = ac0;
                ac0 = __builtin_amdgcn_mfma_f32_16x16x32_f16(a0, bf[0][0], ac0, 0, 0, 0);
                ac1 = __builtin_amdgcn_mfma_f32_16x16x32_f16(a0, bf[1][0], ac1, 0, 0, 0);
                ac2 = __builtin_amdgcn_mfma_f32_16x16x32_f16(a0, bf[2][0], ac2, 0, 0, 0);
                ac3 = __builtin_amdgcn_mfma_f32_16x16x32_f16(a0, bf[3][0], ac3, 0, 0, 0);
                ac0 = __builtin_amdgcn_mfma_f32_16x16x32_f16(a1, bf[0][1], ac0, 0, 0, 0);
                ac1 = __builtin_amdgcn_mfma_f32_16x16x32_f16(a1, bf[1][1], ac1, 0, 0, 0);
                ac2 = __builtin_amdgcn_mfma_f32_16x16x32_f16(a1, bf[2][1], ac2, 0, 0, 0);
                ac3 = __builtin_amdgcn_mfma_f32_16x16x32_f16(a1, bf[3][1], ac3, 0, 0, 0);
#pragma unroll
                for (int reg = 0; reg < 4; ++reg) {
                    int rl = t * 16 + q * 4 + reg;
                    float dvv = sm.p3.sdinv[rl];
                    __half* dst = hp + (size_t)(n0 + rl) * 64 + mm;
                    dst[0]  = __float2half(dvv * ac0[reg]);
                    dst[16] = __float2half(dvv * ac1[reg]);
                    dst[32] = __float2half(dvv * ac2[reg]);
                    dst[48] = __float2half(dvv * ac3[reg]);
                }
            }
            __syncthreads();   // LDS reused next bucket
        }
    }
    gsync(bar, 2);

    // ================= P4: agg1 + relu(+b1) + 64->2 projection ==============
    {
        int lane = tid & 63, slot = lane >> 3, chunk = lane & 7;
        int ngroups = (N + 7) >> 3;
        const float4* hp4 = (const float4*)hp;
        for (int g = blockIdx.x * 4 + (tid >> 6); g < ngroups; g += G * 4) {
            int n = g * 8 + slot;
            int nc = (n < N) ? n : N;
            int start = offsets[nc];
            int end = offsets[(n < N) ? (n + 1) : N];
            int deg = end - start;
            int maxd = deg;
#pragma unroll
            for (int s = 8; s <= 32; s <<= 1) {
                int o = __shfl_xor(maxd, s, 64);
                maxd = (o > maxd) ? o : maxd;
            }
            float4 sr = hp4[(size_t)nc * 8 + chunk];
            __half2 acc0 = ((const __half2*)&sr)[0];
            __half2 acc1 = ((const __half2*)&sr)[1];
            __half2 acc2 = ((const __half2*)&sr)[2];
            __half2 acc3 = ((const __half2*)&sr)[3];
            for (int j0 = 0; j0 < maxd; j0 += 4) {
                int a0 = (j0 + 0 < deg) ? (start + j0 + 0) : E;
                int a1 = (j0 + 1 < deg) ? (start + j0 + 1) : E;
                int a2 = (j0 + 2 < deg) ? (start + j0 + 2) : E;
                int a3 = (j0 + 3 < deg) ? (start + j0 + 3) : E;
                int c0 = scol[a0];
                int c1 = scol[a1];
                int c2 = scol[a2];
                int c3 = scol[a3];
                float4 r0 = hp4[(size_t)c0 * 8 + chunk];
                float4 r1 = hp4[(size_t)c1 * 8 + chunk];
                float4 r2 = hp4[(size_t)c2 * 8 + chunk];
                float4 r3 = hp4[(size_t)c3 * 8 + chunk];
                const __half2* h0 = (const __half2*)&r0;
                const __half2* h1_ = (const __half2*)&r1;
                const __half2* h2_ = (const __half2*)&r2;
                const __half2* h3 = (const __half2*)&r3;
                acc0 = __hadd2(acc0, h0[0]); acc1 = __hadd2(acc1, h0[1]);
                acc2 = __hadd2(acc2, h0[2]); acc3 = __hadd2(acc3, h0[3]);
                acc0 = __hadd2(acc0, h1_[0]); acc1 = __hadd2(acc1, h1_[1]);
                acc2 = __hadd2(acc2, h1_[2]); acc3 = __hadd2(acc3, h1_[3]);
                acc0 = __hadd2(acc0, h2_[0]); acc1 = __hadd2(acc1, h2_[1]);
                acc2 = __hadd2(acc2, h2_[2]); acc3 = __hadd2(acc3, h2_[3]);
                acc0 = __hadd2(acc0, h3[0]); acc1 = __hadd2(acc1, h3[1]);
                acc2 = __hadd2(acc2, h3[2]); acc3 = __hadd2(acc3, h3[3]);
            }
            float af[8];
            { float2 f;
              f = __half22float2(acc0); af[0] = f.x; af[1] = f.y;
              f = __half22float2(acc1); af[2] = f.x; af[3] = f.y;
              f = __half22float2(acc2); af[4] = f.x; af[5] = f.y;
              f = __half22float2(acc3); af[6] = f.x; af[7] = f.y; }
            float dn = dinv[(n < N) ? n : (N - 1)];
            float4 b1a = ((const float4*)b1)[chunk * 2];
            float4 b1b = ((const float4*)b1)[chunk * 2 + 1];
            float h1[8];
            h1[0] = fmaxf(fmaf(dn, af[0], b1a.x), 0.f);
            h1[1] = fmaxf(fmaf(dn, af[1], b1a.y), 0.f);
            h1[2] = fmaxf(fmaf(dn, af[2], b1a.z), 0.f);
            h1[3] = fmaxf(fmaf(dn, af[3], b1a.w), 0.f);
            h1[4] = fmaxf(fmaf(dn, af[4], b1b.x), 0.f);
            h1[5] = fmaxf(fmaf(dn, af[5], b1b.y), 0.f);
            h1[6] = fmaxf(fmaf(dn, af[6], b1b.z), 0.f);
            h1[7] = fmaxf(fmaf(dn, af[7], b1b.w), 0.f);
            float p0 = 0.f, p1 = 0.f;
#pragma unroll
            for (int k = 0; k < 4; ++k) {
                float4 w = ((const float4*)W2)[chunk * 4 + k];
                p0 = fmaf(h1[2 * k], w.x, p0); p1 = fmaf(h1[2 * k], w.y, p1);
                p0 = fmaf(h1[2 * k + 1], w.z, p0); p1 = fmaf(h1[2 * k + 1], w.w, p1);
            }
#pragma unroll
            for (int s = 1; s <= 4; s <<= 1) {
                p0 += __shfl_xor(p0, s, 64);
                p1 += __shfl_xor(p1, s, 64);
            }
            if (chunk == 0 && n < N) h2p[n] = make_float2(dn * p0, dn * p1);
        }
    }
    gsync(bar, 3);

    // ================= P5: agg2 + softmax (16 lanes per node) ===============
    {
        float b20 = b2[0], b21 = b2[1];
        int T = G * 256;
        int sub = tid & 15;
        for (int i = blockIdx.x * 256 + tid; i < N * 16; i += T) {
            int n = i >> 4;
            int start = offsets[n], end = offsets[n + 1];
            float ax = 0.f, ay = 0.f;
            if (sub == 0) { float2 s = h2p[n]; ax = s.x; ay = s.y; }
            for (int j = start + sub; j < end; j += 16) {
                float2 vv = h2p[scol[j]];
                ax += vv.x; ay += vv.y;
            }
#pragma unroll
            for (int s = 1; s <= 8; s <<= 1) {
                ax += __shfl_xor(ax, s, 64);
                ay += __shfl_xor(ay, s, 64);
            }
            if (sub == 0) {
                float dn = dinv[n];
                float l0 = fmaf(dn, ax, b20), l1 = fmaf(dn, ay, b21);
                float m = fmaxf(l0, l1);
                float e0 = __expf(l0 - m), e1 = __expf(l1 - m);
                float inv = 1.0f / (e0 + e1);
                out[n] = make_float2(e0 * inv, e1 * inv);
            }
        }
    }
}

extern "C" void kernel_launch(void* const* d_in, const int* in_sizes, int n_in,
                              void* d_out, int out_size, void* d_ws, size_t ws_size,
                              hipStream_t stream) {
    const float* x  = (const float*)d_in[0];
    const int*   ei = (const int*)d_in[1];
    const float* W1 = (const float*)d_in[2];
    const float* b1 = (const float*)d_in[3];
    const float* W2 = (const float*)d_in[4];
    const float* b2 = (const float*)d_in[5];
    float2* out = (float2*)d_out;

    const int N = in_sizes[0] / 64;     // 100000 (N%16==0, N<2^24)
    const int E = in_sizes[1] / 2;      // 1600000
    const int nb = (N + 255) >> 8;      // 391
    const int* row = ei;
    const int* col = ei + E;

    char* p = (char*)d_ws;
    auto alloc = [&](size_t bytes) -> void* {
        void* r = (void*)p;
        p += (bytes + 255) & ~(size_t)255;
        return r;
    };
    // ctrl: barriers[16] + bcnt[392] + relcur[392] — ONE contiguous block,
    // zeroed by ONE exact memset (R4 lesson; barriers MUST be 0 each call).
    int*   ctrl    = (int*)alloc(800 * 4);
    int*   offsets = (int*)alloc((size_t)(N + 1) * 4);
    float* dinv    = (float*)alloc((size_t)N * 4);
    unsigned* pairbuf = (unsigned*)alloc((size_t)E * 4);
    int*   scol    = (int*)alloc((size_t)(E + 1) * 4);          // +1 sentinel
    __half* hp     = (__half*)alloc((size_t)(N + 1) * 64 * 2);  // +1 zero row
    float2* h2p    = (float2*)alloc((size_t)N * 8);

    hipMemsetAsync(ctrl, 0, 800 * 4, stream);
    k_mega<<<GRID_BLOCKS, 256, 0, stream>>>(x, row, col, W1, b1, W2, b2,
                                            ctrl, offsets, dinv, pairbuf, scol,
                                            hp, h2p, out, N, E, nb);
}

// Round 10
// 165.668 us; speedup vs baseline: 4.3720x; 4.3720x over previous
//
#include <hip/hip_runtime.h>
#include <hip/hip_fp16.h>

// GCN 2-layer forward: out = softmax( A_norm @ relu(A_norm @ (x@W1) + b1) @ W2 + b2 )
// A_norm = D^-1/2 (A + I) D^-1/2, edges are col->row (row = target).
//
// R9 -> R10: mega-kernel with grid barriers was a 4x REGRESSION (barrier spin
// on one cacheline, VGPR 48, 18.9KB LDS, 880k bank conflicts). Reverted to
// split dispatches; kept only barrier-free fusions:
//  - fixed-capacity buckets (CAP=8192/bucket, mean 4092, +64 sigma): kills the
//    hist kernel and all global prefix scans; CSR carries deg[] (scol has
//    gaps between buckets).
//  - gemm1 (MFMA) fused INTO the per-bucket sort block (dinv via LDS).
//  - agg1: 8-deep unrolled gathers, __launch_bounds__(256,4).
// 5 dispatches: memset(relcur) -> bin -> sort+gemm -> agg1 -> agg2.

typedef _Float16 f16x8 __attribute__((ext_vector_type(8)));
typedef float f32x4 __attribute__((ext_vector_type(4)));

#define CAPSH 13
#define CAP (1 << CAPSH)          // per-bucket pairbuf/scol capacity

// ---- 1. bin edges into per-bucket fixed slices (coalesced packed runs) -----
__global__ __launch_bounds__(256) void k_bin(const int* __restrict__ row,
                                             const int* __restrict__ col,
                                             int* __restrict__ relcur,
                                             unsigned* __restrict__ pairbuf,
                                             __half* __restrict__ hp,
                                             int E, int nb, int N) {
    __shared__ unsigned items[4096];        // (r&255)<<24 | col
    __shared__ unsigned short bktid[4096];
    __shared__ int cnt[392];
    __shared__ int start0[392];
    __shared__ int cursor[392];
    __shared__ int gbase[392];

    int tid = threadIdx.x;
    int base = blockIdx.x * 4096;
    int m = E - base; if (m > 4096) m = 4096;

    for (int t = tid; t < nb; t += 256) cnt[t] = 0;
    __syncthreads();
    for (int i = tid; i < m; i += 256) atomicAdd(&cnt[row[base + i] >> 8], 1);
    __syncthreads();
    // wave0: exclusive scan of tile counts -> start0, cursor
    if (tid < 64) {
        int lane = tid, running = 0;
        for (int ch = 0; ch < 7; ++ch) {
            int idx = ch * 64 + lane;
            int v = (idx < nb) ? cnt[idx] : 0;
            int s = v;
#pragma unroll
            for (int off = 1; off < 64; off <<= 1) {
                int t = __shfl_up(s, off, 64);
                if (lane >= off) s += t;
            }
            if (idx < nb) { start0[idx] = running + s - v; cursor[idx] = running + s - v; }
            running += __shfl(s, 63, 64);
        }
    }
    __syncthreads();
    for (int i = tid; i < m; i += 256) {
        int r = row[base + i];
        int c = col[base + i];
        int b = r >> 8;
        int pos = atomicAdd(&cursor[b], 1);
        items[pos] = ((unsigned)(r & 255) << 24) | (unsigned)c;
        bktid[pos] = (unsigned short)b;
    }
    __syncthreads();
    // claim global space: bucket b's slice starts at b*CAP
    for (int t = tid; t < nb; t += 256) {
        int cv = cnt[t];
        if (cv > 0) gbase[t] = (t << CAPSH) + atomicAdd(&relcur[t], cv);
    }
    __syncthreads();
    for (int i = tid; i < m; i += 256) {
        int b = bktid[i];
        pairbuf[gbase[b] + (i - start0[b])] = items[i];
    }
    if (blockIdx.x == 0 && tid < 32) ((int*)(hp + (size_t)N * 64))[tid] = 0;  // zero row
}

// ---- 2. per-bucket counting sort -> scol/offsets/deg/dinv, + MFMA gemm -----
// One block per bucket. After the sort, the same block computes
// hp[n] = fp16(dinv[n] * x[n]@W1) for its 256 nodes (dinv via LDS).
__global__ __launch_bounds__(256, 4) void k_sortgemm(const unsigned* __restrict__ pairbuf,
                                                     const int* __restrict__ relcur,
                                                     const float* __restrict__ x,
                                                     const float* __restrict__ W1,
                                                     int* __restrict__ scol,
                                                     int* __restrict__ offsets,
                                                     int* __restrict__ deg,
                                                     float* __restrict__ dinv,
                                                     __half* __restrict__ hp,
                                                     int N, int nb) {
    __shared__ int cnt[256];
    __shared__ int tmp[256];
    __shared__ int cur[256];
    __shared__ float sdinv[256];
    int b = blockIdx.x;
    int tid = threadIdx.x;
    int lane = tid & 63, q = lane >> 4, mm = lane & 15;
    // B-frags (W1 fp16), loaded once per block: B[k][n], n=nt*16+mm, k=kk*32+q*8+j
    f16x8 bf[4][2];
#pragma unroll
    for (int nt = 0; nt < 4; ++nt)
#pragma unroll
        for (int kk = 0; kk < 2; ++kk)
#pragma unroll
            for (int j = 0; j < 8; ++j)
                bf[nt][kk][j] = (_Float16)W1[(kk * 32 + q * 8 + j) * 64 + nt * 16 + mm];

    int lo = b << CAPSH;
    int hi = lo + relcur[b];
    cnt[tid] = 0;
    __syncthreads();
    for (int i = lo + tid; i < hi; i += 256)
        atomicAdd(&cnt[pairbuf[i] >> 24], 1);
    __syncthreads();
    int cv = cnt[tid];
    tmp[tid] = cv;
    __syncthreads();
    for (int d = 1; d < 256; d <<= 1) {
        int t = (tid >= d) ? tmp[tid - d] : 0;
        __syncthreads();
        if (tid >= d) tmp[tid] += t;
        __syncthreads();
    }
    int excl = tmp[tid] - cv;
    int n = (b << 8) + tid;
    float dv = rsqrtf((float)(cv + 1));     // +1 self-loop
    if (n < N) { offsets[n] = lo + excl; deg[n] = cv; dinv[n] = dv; }
    sdinv[tid] = dv;
    cur[tid] = lo + excl;
    if (b == 0 && tid == 0) {
        offsets[N] = 0; deg[N] = 0;         // clamped-node entry
        scol[nb << CAPSH] = N;              // sentinel -> zero row
    }
    __syncthreads();
    for (int i = lo + tid; i < hi; i += 256) {
        unsigned it = pairbuf[i];
        int pos = atomicAdd(&cur[it >> 24], 1);
        scol[pos] = (int)(it & 0xFFFFFFu);
    }
    __syncthreads();
    // gemm this bucket's nodes (nn is a multiple of 16)
    int n0 = b << 8;
    int nn = N - n0; if (nn > 256) nn = 256;
    for (int t = (tid >> 6); t < (nn >> 4); t += 4) {
        const float* xrow = x + (size_t)(n0 + t * 16 + mm) * 64;
        float4 u0 = *(const float4*)(xrow + q * 8);
        float4 u1 = *(const float4*)(xrow + q * 8 + 4);
        float4 u2 = *(const float4*)(xrow + 32 + q * 8);
        float4 u3 = *(const float4*)(xrow + 32 + q * 8 + 4);
        f16x8 a0, a1;
        a0[0] = (_Float16)u0.x; a0[1] = (_Float16)u0.y; a0[2] = (_Float16)u0.z; a0[3] = (_Float16)u0.w;
        a0[4] = (_Float16)u1.x; a0[5] = (_Float16)u1.y; a0[6] = (_Float16)u1.z; a0[7] = (_Float16)u1.w;
        a1[0] = (_Float16)u2.x; a1[1] = (_Float16)u2.y; a1[2] = (_Float16)u2.z; a1[3] = (_Float16)u2.w;
        a1[4] = (_Float16)u3.x; a1[5] = (_Float16)u3.y; a1[6] = (_Float16)u3.z; a1[7] = (_Float16)u3.w;
        f32x4 ac0 = {0.f, 0.f, 0.f, 0.f}, ac1 = ac0, ac2 = ac0, ac3 = ac0;
        ac0 = __builtin_amdgcn_mfma_f32_16x16x32_f16(a0, bf[0][0], ac0, 0, 0, 0);
        ac1 = __builtin_amdgcn_mfma_f32_16x16x32_f16(a0, bf[1][0], ac1, 0, 0, 0);
        ac2 = __builtin_amdgcn_mfma_f32_16x16x32_f16(a0, bf[2][0], ac2, 0, 0, 0);
        ac3 = __builtin_amdgcn_mfma_f32_16x16x32_f16(a0, bf[3][0], ac3, 0, 0, 0);
        ac0 = __builtin_amdgcn_mfma_f32_16x16x32_f16(a1, bf[0][1], ac0, 0, 0, 0);
        ac1 = __builtin_amdgcn_mfma_f32_16x16x32_f16(a1, bf[1][1], ac1, 0, 0, 0);
        ac2 = __builtin_amdgcn_mfma_f32_16x16x32_f16(a1, bf[2][1], ac2, 0, 0, 0);
        ac3 = __builtin_amdgcn_mfma_f32_16x16x32_f16(a1, bf[3][1], ac3, 0, 0, 0);
#pragma unroll
        for (int reg = 0; reg < 4; ++reg) {
            int rl = t * 16 + q * 4 + reg;
            float dvv = sdinv[rl];
            __half* dst = hp + (size_t)(n0 + rl) * 64 + mm;
            dst[0]  = __float2half(dvv * ac0[reg]);
            dst[16] = __float2half(dvv * ac1[reg]);
            dst[32] = __float2half(dvv * ac2[reg]);
            dst[48] = __float2half(dvv * ac3[reg]);
        }
    }
}

// ---- 3. layer-1 agg + relu(+b1) + 64->2 projection, fused ------------------
// Wave = 8 nodes; slot=lane>>3 owns a node, chunk=lane&7 owns 16B of its row.
// 8-deep unrolled gathers (8 scol loads + 8 row gathers in flight per slot).
__global__ __launch_bounds__(256, 4) void k_agg1(const __half* __restrict__ hp,
                                                 const int* __restrict__ offsets,
                                                 const int* __restrict__ deg,
                                                 const int* __restrict__ scol,
                                                 const float* __restrict__ dinv,
                                                 const float* __restrict__ b1,
                                                 const float* __restrict__ W2,
                                                 float2* __restrict__ h2p,
                                                 int N, int SENT) {
    int lane = threadIdx.x & 63;
    int slot = lane >> 3;
    int chunk = lane & 7;
    int wid = (int)((blockIdx.x * 256 + threadIdx.x) >> 6);
    int n = wid * 8 + slot;
    int nc = (n < N) ? n : N;                 // row N of hp is the zero row
    int start = offsets[nc];
    int dg = deg[nc];                         // deg[N] = 0
    int maxd = dg;
#pragma unroll
    for (int s = 8; s <= 32; s <<= 1) {
        int o = __shfl_xor(maxd, s, 64);
        maxd = (o > maxd) ? o : maxd;
    }
    const float4* hp4 = (const float4*)hp;    // row stride = 8 float4
    float4 sr = hp4[(size_t)nc * 8 + chunk];  // self term
    __half2 acc0 = ((const __half2*)&sr)[0];
    __half2 acc1 = ((const __half2*)&sr)[1];
    __half2 acc2 = ((const __half2*)&sr)[2];
    __half2 acc3 = ((const __half2*)&sr)[3];
    for (int j0 = 0; j0 < maxd; j0 += 8) {
        int c[8];
#pragma unroll
        for (int u = 0; u < 8; ++u)
            c[u] = scol[(j0 + u < dg) ? (start + j0 + u) : SENT];  // SENT -> N
        float4 r[8];
#pragma unroll
        for (int u = 0; u < 8; ++u) r[u] = hp4[(size_t)c[u] * 8 + chunk];
#pragma unroll
        for (int u = 0; u < 8; ++u) {
            const __half2* hh = (const __half2*)&r[u];
            acc0 = __hadd2(acc0, hh[0]); acc1 = __hadd2(acc1, hh[1]);
            acc2 = __hadd2(acc2, hh[2]); acc3 = __hadd2(acc3, hh[3]);
        }
    }
    float af[8];
    { float2 f;
      f = __half22float2(acc0); af[0] = f.x; af[1] = f.y;
      f = __half22float2(acc1); af[2] = f.x; af[3] = f.y;
      f = __half22float2(acc2); af[4] = f.x; af[5] = f.y;
      f = __half22float2(acc3); af[6] = f.x; af[7] = f.y; }
    float dn = dinv[(n < N) ? n : (N - 1)];
    float4 b1a = ((const float4*)b1)[chunk * 2];
    float4 b1b = ((const float4*)b1)[chunk * 2 + 1];
    float h1[8];
    h1[0] = fmaxf(fmaf(dn, af[0], b1a.x), 0.f);
    h1[1] = fmaxf(fmaf(dn, af[1], b1a.y), 0.f);
    h1[2] = fmaxf(fmaf(dn, af[2], b1a.z), 0.f);
    h1[3] = fmaxf(fmaf(dn, af[3], b1a.w), 0.f);
    h1[4] = fmaxf(fmaf(dn, af[4], b1b.x), 0.f);
    h1[5] = fmaxf(fmaf(dn, af[5], b1b.y), 0.f);
    h1[6] = fmaxf(fmaf(dn, af[6], b1b.z), 0.f);
    h1[7] = fmaxf(fmaf(dn, af[7], b1b.w), 0.f);
    float p0 = 0.f, p1 = 0.f;
#pragma unroll
    for (int k = 0; k < 4; ++k) {   // float4 = W2 rows {8c+2k, 8c+2k+1}
        float4 w = ((const float4*)W2)[chunk * 4 + k];
        p0 = fmaf(h1[2 * k], w.x, p0); p1 = fmaf(h1[2 * k], w.y, p1);
        p0 = fmaf(h1[2 * k + 1], w.z, p0); p1 = fmaf(h1[2 * k + 1], w.w, p1);
    }
#pragma unroll
    for (int s = 1; s <= 4; s <<= 1) {  // reduce across chunk (bits 0,1,2)
        p0 += __shfl_xor(p0, s, 64);
        p1 += __shfl_xor(p1, s, 64);
    }
    if (chunk == 0 && n < N) h2p[n] = make_float2(dn * p0, dn * p1);  // pre-scaled
}

// ---- 4. layer-2 agg + softmax: 16 lanes per node ---------------------------
__global__ __launch_bounds__(256) void k_agg2(const float2* __restrict__ h2p,
                                              const int* __restrict__ offsets,
                                              const int* __restrict__ deg,
                                              const int* __restrict__ scol,
                                              const float* __restrict__ dinv,
                                              const float* __restrict__ b2,
                                              float2* __restrict__ out, int N) {
    int gtid = blockIdx.x * 256 + threadIdx.x;
    int n = gtid >> 4;
    int sub = threadIdx.x & 15;
    if (n >= N) return;
    int start = offsets[n], end = start + deg[n];
    float ax = 0.f, ay = 0.f;
    if (sub == 0) { float2 s = h2p[n]; ax = s.x; ay = s.y; }   // self (pre-scaled)
    for (int j = start + sub; j < end; j += 16) {
        float2 v = h2p[scol[j]];
        ax += v.x; ay += v.y;
    }
#pragma unroll
    for (int s = 1; s <= 8; s <<= 1) {
        ax += __shfl_xor(ax, s, 64);
        ay += __shfl_xor(ay, s, 64);
    }
    if (sub == 0) {
        float dn = dinv[n];
        float l0 = fmaf(dn, ax, b2[0]), l1 = fmaf(dn, ay, b2[1]);
        float m = fmaxf(l0, l1);
        float e0 = __expf(l0 - m), e1 = __expf(l1 - m);
        float inv = 1.0f / (e0 + e1);
        out[n] = make_float2(e0 * inv, e1 * inv);
    }
}

extern "C" void kernel_launch(void* const* d_in, const int* in_sizes, int n_in,
                              void* d_out, int out_size, void* d_ws, size_t ws_size,
                              hipStream_t stream) {
    const float* x  = (const float*)d_in[0];
    const int*   ei = (const int*)d_in[1];
    const float* W1 = (const float*)d_in[2];
    const float* b1 = (const float*)d_in[3];
    const float* W2 = (const float*)d_in[4];
    const float* b2 = (const float*)d_in[5];
    float2* out = (float2*)d_out;

    const int N = in_sizes[0] / 64;     // 100000 (N%16==0, N<2^24)
    const int E = in_sizes[1] / 2;      // 1600000
    const int nb = (N + 255) >> 8;      // 391
    const int SENT = nb << CAPSH;
    const int* row = ei;
    const int* col = ei + E;

    char* p = (char*)d_ws;
    auto alloc = [&](size_t bytes) -> void* {
        void* r = (void*)p;
        p += (bytes + 255) & ~(size_t)255;
        return r;
    };
    int*   relcur  = (int*)alloc((size_t)nb * 4);               // memset exact (R4 lesson)
    int*   offsets = (int*)alloc((size_t)(N + 1) * 4);
    int*   deg     = (int*)alloc((size_t)(N + 1) * 4);
    float* dinv    = (float*)alloc((size_t)N * 4);
    unsigned* pairbuf = (unsigned*)alloc((size_t)nb * CAP * 4);
    int*   scol    = (int*)alloc(((size_t)nb * CAP + 1) * 4);   // +1 sentinel
    __half* hp     = (__half*)alloc((size_t)(N + 1) * 64 * 2);  // +1 zero row
    float2* h2p    = (float2*)alloc((size_t)N * 8);

    const int nTile = (E + 4095) / 4096;  // 391

    hipMemsetAsync(relcur, 0, (size_t)nb * 4, stream);
    k_bin<<<nTile, 256, 0, stream>>>(row, col, relcur, pairbuf, hp, E, nb, N);
    k_sortgemm<<<nb, 256, 0, stream>>>(pairbuf, relcur, x, W1, scol, offsets, deg, dinv, hp, N, nb);
    const int nwaves = (N + 7) / 8;                  // 8 nodes per wave
    k_agg1<<<(nwaves + 3) / 4, 256, 0, stream>>>(hp, offsets, deg, scol, dinv, b1, W2, h2p, N, SENT);
    k_agg2<<<(N * 16 + 255) / 256, 256, 0, stream>>>(h2p, offsets, deg, scol, dinv, b2, out, N);
}